// Round 8
// baseline (98.592 us; speedup 1.0000x reference)
//
#include <hip/hip_runtime.h>
#include <math.h>

#define BB 2
#define NN 2048
#define EE 256
#define HH 8
#define DD 32

typedef __attribute__((ext_vector_type(8))) short short8;
typedef __attribute__((ext_vector_type(4))) float f32x4;

__device__ inline unsigned short f2bf(float f) {
  union { float f; unsigned int u; } a; a.f = f;
  unsigned int r = a.u + 0x7FFFu + ((a.u >> 16) & 1u);
  return (unsigned short)(r >> 16);
}
__device__ inline float bf2f(short s) {
  union { unsigned int u; float f; } a;
  a.u = ((unsigned int)(unsigned short)s) << 16;
  return a.f;
}

// ---------------------------------------------------------------------------
// Cast projection weights to bf16. in_w: 768x256, out_w: 256x256.
// ---------------------------------------------------------------------------
__global__ __launch_bounds__(256) void cast_w_kernel(const float* __restrict__ in_w,
                                                     const float* __restrict__ out_w,
                                                     unsigned short* __restrict__ in_wb,
                                                     unsigned short* __restrict__ out_wb) {
  int i = blockIdx.x * 256 + threadIdx.x;
  float4 v;
  unsigned short* dst;
  if (i < 49152) {
    v = ((const float4*)in_w)[i];
    dst = in_wb + (size_t)i * 4;
  } else {
    v = ((const float4*)out_w)[i - 49152];
    dst = out_wb + (size_t)(i - 49152) * 4;
  }
  ushort4 u;
  u.x = f2bf(v.x); u.y = f2bf(v.y); u.z = f2bf(v.z); u.w = f2bf(v.w);
  *(ushort4*)dst = u;
}

// ---------------------------------------------------------------------------
// tau2[row][h] = (dot(feat,tau_w[h]) + tau_b[h]) * log2e;  cxy = centers;
// also casts feat -> featb (bf16).
// ---------------------------------------------------------------------------
__global__ __launch_bounds__(256) void tau_cxy_kernel(const float* __restrict__ feat,
                                                      const float* __restrict__ tau_w,
                                                      const float* __restrict__ tau_b,
                                                      const float* __restrict__ bbox,
                                                      float* __restrict__ tau2,
                                                      float2* __restrict__ cxy,
                                                      unsigned short* __restrict__ featb) {
  int idx = blockIdx.x * 256 + threadIdx.x;
  int row = idx >> 3, h = idx & 7;
  const float4* f = (const float4*)(feat + (size_t)row * EE);
  const float4* w = (const float4*)(tau_w + (size_t)h * EE);
  float s = 0.f;
#pragma unroll 8
  for (int e = 0; e < EE / 4; ++e) {
    float4 a = f[e], b4 = w[e];
    s = fmaf(a.x, b4.x, s);
    s = fmaf(a.y, b4.y, s);
    s = fmaf(a.z, b4.z, s);
    s = fmaf(a.w, b4.w, s);
    if ((e >> 3) == h) {
      ushort4 u;
      u.x = f2bf(a.x); u.y = f2bf(a.y); u.z = f2bf(a.z); u.w = f2bf(a.w);
      *(ushort4*)(featb + (size_t)row * EE + e * 4) = u;
    }
  }
  tau2[idx] = (s + tau_b[h]) * 1.4426950408889634f;
  if (h == 0) {
    float2 c;
    c.x = bbox[(size_t)row * 4 + 0];
    c.y = bbox[(size_t)row * 4 + 1];
    cxy[row] = c;
  }
}

// ---------------------------------------------------------------------------
// Pairwise -dist, bf16, tiled to match attn fragments exactly:
// nds[((b*128+qt)*32 + jt)*1024 + lane*16 + (t*4+r)] = -dist(q15, jt*64+t*16+g*4+r)
// grid (BB*128, 8), block 256 (4 waves; wave w -> jt = blockIdx.y*4 + w).
// Computed ONCE per (b,i,j); shared by all 8 heads in attn.
// ---------------------------------------------------------------------------
__global__ __launch_bounds__(256) void dist_kernel(const float2* __restrict__ cxy,
                                                   unsigned short* __restrict__ nds) {
  int bq = blockIdx.x;
  int b = bq >> 7, qt = bq & 127;
  int tid = threadIdx.x;
  int w = tid >> 6, lane = tid & 63;
  int q15 = lane & 15, g = lane >> 4;
  int jt = blockIdx.y * 4 + w;

  float2 ci = cxy[b * NN + qt * 16 + q15];
  const float2* cb = cxy + b * NN + jt * 64;

  float nd[16];
#pragma unroll
  for (int t = 0; t < 4; ++t) {
    float4 c01 = *(const float4*)(cb + t * 16 + g * 4);
    float4 c23 = *(const float4*)(cb + t * 16 + g * 4 + 2);
    float cx[4] = {c01.x, c01.z, c23.x, c23.z};
    float cy[4] = {c01.y, c01.w, c23.y, c23.w};
#pragma unroll
    for (int r = 0; r < 4; ++r) {
      float dx = ci.x - cx[r], dy = ci.y - cy[r];
      nd[t * 4 + r] = -__builtin_amdgcn_sqrtf(fmaf(dy, dy, dx * dx));
    }
  }
  unsigned int u[8];
#pragma unroll
  for (int i = 0; i < 8; ++i)
    asm("v_cvt_pk_bf16_f32 %0, %1, %2" : "=v"(u[i]) : "v"(nd[2 * i]), "v"(nd[2 * i + 1]));
  unsigned short* dst = nds + ((size_t)(b * 128 + qt) * 32 + jt) * 1024 + lane * 16;
  *(uint4*)dst = make_uint4(u[0], u[1], u[2], u[3]);
  *(uint4*)(dst + 8) = make_uint4(u[4], u[5], u[6], u[7]);
}

// ---------------------------------------------------------------------------
// bf16 MFMA GEMM (validated round 7). MODE 0: qkv epilogue -> qb/kh/vpi, with
// Q pre-scaled by (1/sqrt(D))*log2e. MODE 1: out = v + resid (fp32).
// ---------------------------------------------------------------------------
template <int MODE>
__global__ __launch_bounds__(256) void gemm_mfma_kernel(const unsigned short* __restrict__ Ab,
                                                        const unsigned short* __restrict__ Wb,
                                                        const float* __restrict__ bias,
                                                        const float* __restrict__ resid,
                                                        float* __restrict__ Cf,
                                                        unsigned short* __restrict__ qb,
                                                        unsigned short* __restrict__ kh,
                                                        unsigned short* __restrict__ vpi) {
  int tid = threadIdx.x;
  int wv = tid >> 6, lane = tid & 63;
  int p = lane & 15, g = lane >> 4;
  int mW = blockIdx.y * 64 + wv * 16;
  int nB = blockIdx.x * 64;

  const unsigned short* ap = Ab + (size_t)(mW + p) * 256 + g * 8;
  const unsigned short* wp = Wb + (size_t)(nB + p) * 256 + g * 8;

  f32x4 acc[4] = {{0.f, 0.f, 0.f, 0.f}, {0.f, 0.f, 0.f, 0.f},
                  {0.f, 0.f, 0.f, 0.f}, {0.f, 0.f, 0.f, 0.f}};
#pragma unroll
  for (int kk = 0; kk < 8; ++kk) {
    short8 af = *(const short8*)(ap + kk * 32);
#pragma unroll
    for (int t = 0; t < 4; ++t) {
      short8 wf = *(const short8*)(wp + (size_t)t * 16 * 256 + kk * 32);
      acc[t] = __builtin_amdgcn_mfma_f32_16x16x32_bf16(af, wf, acc[t], 0, 0, 0);
    }
  }

#pragma unroll
  for (int t = 0; t < 4; ++t) {
    int n = nB + t * 16 + p;
    float bn = bias[n];
#pragma unroll
    for (int r = 0; r < 4; ++r) {
      int m = mW + g * 4 + r;
      float v = acc[t][r] + bn;
      if (MODE == 1) {
        Cf[(size_t)m * 256 + n] = v + resid[(size_t)m * 256 + n];
      } else {
        int b = m >> 11, tok = m & 2047;
        if (n < 256) {
          // Q: fold in 1/sqrt(32) * log2e so attn score = st + nd*tau2 directly
          qb[(size_t)m * 256 + n] = f2bf(v * 0.25506659272582955f);
        } else if (n < 512) {
          int h = (n - 256) >> 5, d = n & 31;
          kh[((size_t)(b * 8 + h) * NN + tok) * 32 + d] = f2bf(v);
        } else {
          int h = (n - 512) >> 5, d = n & 31;
          int cp = ((tok & 15) << 1) | ((tok >> 4) & 1);
          vpi[(((size_t)(b * 8 + h) * 64 + (tok >> 5)) * 32 + d) * 32 + cp] = f2bf(v);
        }
      }
    }
  }
}

// ---------------------------------------------------------------------------
// MFMA flash attention, fixed-reference softmax (clamped, NaN-proof):
//   p = exp2(min(st + nd*tau2, 30)); linear partials; plain-sum merge.
// 4-wave K-split; contiguous kh/vpi/nds frag layouts; K prefetch.
// ---------------------------------------------------------------------------
__global__ __launch_bounds__(256) void attn_kernel(const unsigned short* __restrict__ qb,
                                                   const unsigned short* __restrict__ kh,
                                                   const unsigned short* __restrict__ vpi,
                                                   const unsigned short* __restrict__ nds,
                                                   const float* __restrict__ tau2,
                                                   unsigned short* __restrict__ ob) {
  __shared__ float accT[4][32][17];
  __shared__ float lT[4][16];
  __shared__ float linv[16];

  int bh = blockIdx.x;
  int b = bh >> 3, h = bh & 7;
  int qtb = blockIdx.y;
  int tid = threadIdx.x;
  int w = tid >> 6;
  int lane = tid & 63;
  int q15 = lane & 15, g = lane >> 4;
  int rowq = b * NN + qtb * 16 + q15;

  short8 qf = *(const short8*)(qb + (size_t)rowq * 256 + h * 32 + g * 8);
  float t2 = tau2[(size_t)rowq * HH + h];

  float l = 0.f;
  f32x4 acc0 = {0.f, 0.f, 0.f, 0.f}, acc1 = {0.f, 0.f, 0.f, 0.f};

  const unsigned short* kb = kh + (size_t)bh * NN * 32 + q15 * 32 + g * 8;
  const unsigned short* vb = vpi + (size_t)bh * NN * 32 + q15 * 32 + g * 8;
  const unsigned short* ndb = nds + (size_t)(b * 128 + qtb) * 32 * 1024 + lane * 16;

  int j0base = w * 512;

  short8 kf[2][4];
  short8 vf[2][2];

#pragma unroll
  for (int t = 0; t < 4; ++t)
    kf[0][t] = *(const short8*)(kb + (size_t)(j0base + t * 16) * 32);

#pragma unroll
  for (int tt = 0; tt < 8; ++tt) {
    const int cur = tt & 1, nxt = cur ^ 1;
    const int j0 = j0base + tt * 64;
    const int jt = j0 >> 6;
    if (tt < 7) {
#pragma unroll
      for (int t = 0; t < 4; ++t)
        kf[nxt][t] = *(const short8*)(kb + (size_t)(j0 + 64 + t * 16) * 32);
    }
#pragma unroll
    for (int t2i = 0; t2i < 2; ++t2i)
#pragma unroll
      for (int dh = 0; dh < 2; ++dh)
        vf[t2i][dh] = *(const short8*)(vb + (size_t)((j0 >> 5) + t2i) * 1024 + dh * 512);
    // -dist frags (bf16, lane-contiguous 32B)
    short8 n0 = *(const short8*)(ndb + (size_t)jt * 1024);
    short8 n1 = *(const short8*)(ndb + (size_t)jt * 1024 + 8);
    // ---- S^T tiles: 4x mfma (A = K rows, B = Q-prescaled) ----
    f32x4 st[4];
#pragma unroll
    for (int t = 0; t < 4; ++t)
      st[t] = __builtin_amdgcn_mfma_f32_16x16x32_bf16(kf[cur][t], qf, (f32x4){0.f, 0.f, 0.f, 0.f}, 0, 0, 0);
    // ---- score + exp2 (fixed reference, clamped) ----
    float p[16], lsum = 0.f;
#pragma unroll
    for (int i = 0; i < 16; ++i) {
      float ndf = bf2f(i < 8 ? n0[i] : n1[i - 8]);
      float e = fminf(fmaf(ndf, t2, st[i >> 2][i & 3]), 30.f);
      p[i] = __builtin_amdgcn_exp2f(e);
      lsum += p[i];
    }
    l += lsum;
    // ---- pack P to bf16 B-frags: u[wq] pairs keys (k, k+16) ----
    union { short8 v; unsigned int u[4]; } pf[2];
#pragma unroll
    for (int t2i = 0; t2i < 2; ++t2i)
#pragma unroll
      for (int wq = 0; wq < 4; ++wq) {
        float lo = p[t2i * 8 + wq];
        float hi = p[t2i * 8 + 4 + wq];
        asm("v_cvt_pk_bf16_f32 %0, %1, %2" : "=v"(pf[t2i].u[wq]) : "v"(lo), "v"(hi));
      }
    // ---- PV: 4x mfma, acc in O^T layout (col=q, row=d) ----
    acc0 = __builtin_amdgcn_mfma_f32_16x16x32_bf16(vf[0][0], pf[0].v, acc0, 0, 0, 0);
    acc1 = __builtin_amdgcn_mfma_f32_16x16x32_bf16(vf[0][1], pf[0].v, acc1, 0, 0, 0);
    acc0 = __builtin_amdgcn_mfma_f32_16x16x32_bf16(vf[1][0], pf[1].v, acc0, 0, 0, 0);
    acc1 = __builtin_amdgcn_mfma_f32_16x16x32_bf16(vf[1][1], pf[1].v, acc1, 0, 0, 0);
  }

  // l currently holds this lane's 16-of-64 keys per tile; acc holds the full
  // key-sum. Reduce across g-groups sharing the query.
  l += __shfl_xor(l, 16);
  l += __shfl_xor(l, 32);

#pragma unroll
  for (int r = 0; r < 4; ++r) {
    accT[w][g * 4 + r][q15] = acc0[r];
    accT[w][16 + g * 4 + r][q15] = acc1[r];
  }
  if (g == 0) lT[w][q15] = l;
  __syncthreads();

  if (tid < 16) {
    float L = lT[0][tid] + lT[1][tid] + lT[2][tid] + lT[3][tid];
    linv[tid] = 1.f / fmaxf(L, 1e-30f);
  }
  __syncthreads();

#pragma unroll
  for (int ii = 0; ii < 2; ++ii) {
    int i = tid + ii * 256;
    int q = i >> 5, d = i & 31;
    float ov = (accT[0][d][q] + accT[1][d][q] + accT[2][d][q] + accT[3][d][q]) * linv[q];
    ob[((size_t)b * NN + qtb * 16 + q) * EE + h * 32 + d] = f2bf(ov);
  }
}

extern "C" void kernel_launch(void* const* d_in, const int* in_sizes, int n_in,
                              void* d_out, int out_size, void* d_ws, size_t ws_size,
                              hipStream_t stream) {
  const float* bbox  = (const float*)d_in[0];
  const float* feat  = (const float*)d_in[1];
  const float* in_w  = (const float*)d_in[2];
  const float* in_b  = (const float*)d_in[3];
  const float* out_w = (const float*)d_in[4];
  const float* out_b = (const float*)d_in[5];
  const float* tau_w = (const float*)d_in[6];
  const float* tau_b = (const float*)d_in[7];
  float* out = (float*)d_out;

  unsigned short* ob     = (unsigned short*)d_ws;   // 1M bf16
  unsigned short* featb  = ob + 1048576;            // 1M bf16
  unsigned short* qb     = featb + 1048576;         // 1M bf16
  unsigned short* kh     = qb + 1048576;            // 1M bf16
  unsigned short* vpi    = kh + 1048576;            // 1M bf16
  unsigned short* in_wb  = vpi + 1048576;           // 196608 bf16
  unsigned short* out_wb = in_wb + 196608;          // 65536 bf16
  float* tau2 = (float*)(out_wb + 65536);           // 32768 f32
  float2* cxy = (float2*)(tau2 + 32768);            // 4096 float2
  unsigned short* nds = (unsigned short*)(cxy + 4096);  // 8,388,608 bf16 (16.8MB)

  cast_w_kernel<<<dim3(256), 256, 0, stream>>>(in_w, out_w, in_wb, out_wb);
  tau_cxy_kernel<<<dim3(128), 256, 0, stream>>>(feat, tau_w, tau_b, bbox, tau2, cxy, featb);
  dist_kernel<<<dim3(BB * 128, 8), 256, 0, stream>>>(cxy, nds);
  gemm_mfma_kernel<0><<<dim3(12, 64), 256, 0, stream>>>(featb, in_wb, in_b, nullptr, nullptr,
                                                        qb, kh, vpi);
  attn_kernel<<<dim3(BB * HH, NN / 16), 256, 0, stream>>>(qb, kh, vpi, nds, tau2, ob);
  gemm_mfma_kernel<1><<<dim3(4, 64), 256, 0, stream>>>(ob, out_wb, out_b, feat, out,
                                                       nullptr, nullptr, nullptr);
}

// Round 9
// 92.635 us; speedup vs baseline: 1.0643x; 1.0643x over previous
//
#include <hip/hip_runtime.h>
#include <math.h>

#define BB 2
#define NN 2048
#define EE 256
#define HH 8
#define DD 32

typedef __attribute__((ext_vector_type(8))) short short8;
typedef __attribute__((ext_vector_type(4))) float f32x4;

__device__ inline unsigned short f2bf(float f) {
  union { float f; unsigned int u; } a; a.f = f;
  unsigned int r = a.u + 0x7FFFu + ((a.u >> 16) & 1u);
  return (unsigned short)(r >> 16);
}
__device__ inline float bf2f(short s) {
  union { unsigned int u; float f; } a;
  a.u = ((unsigned int)(unsigned short)s) << 16;
  return a.f;
}

// ---------------------------------------------------------------------------
// Cast projection weights to bf16. in_w: 768x256, out_w: 256x256.
// ---------------------------------------------------------------------------
__global__ __launch_bounds__(256) void cast_w_kernel(const float* __restrict__ in_w,
                                                     const float* __restrict__ out_w,
                                                     unsigned short* __restrict__ in_wb,
                                                     unsigned short* __restrict__ out_wb) {
  int i = blockIdx.x * 256 + threadIdx.x;
  float4 v;
  unsigned short* dst;
  if (i < 49152) {
    v = ((const float4*)in_w)[i];
    dst = in_wb + (size_t)i * 4;
  } else {
    v = ((const float4*)out_w)[i - 49152];
    dst = out_wb + (size_t)(i - 49152) * 4;
  }
  ushort4 u;
  u.x = f2bf(v.x); u.y = f2bf(v.y); u.z = f2bf(v.z); u.w = f2bf(v.w);
  *(ushort4*)dst = u;
}

// ---------------------------------------------------------------------------
// tau2[row][h] = (dot(feat,tau_w[h]) + tau_b[h]) * log2e;  cxy = centers;
// also casts feat -> featb (bf16).
// ---------------------------------------------------------------------------
__global__ __launch_bounds__(256) void tau_cxy_kernel(const float* __restrict__ feat,
                                                      const float* __restrict__ tau_w,
                                                      const float* __restrict__ tau_b,
                                                      const float* __restrict__ bbox,
                                                      float* __restrict__ tau2,
                                                      float2* __restrict__ cxy,
                                                      unsigned short* __restrict__ featb) {
  int idx = blockIdx.x * 256 + threadIdx.x;
  int row = idx >> 3, h = idx & 7;
  const float4* f = (const float4*)(feat + (size_t)row * EE);
  const float4* w = (const float4*)(tau_w + (size_t)h * EE);
  float s = 0.f;
#pragma unroll 8
  for (int e = 0; e < EE / 4; ++e) {
    float4 a = f[e], b4 = w[e];
    s = fmaf(a.x, b4.x, s);
    s = fmaf(a.y, b4.y, s);
    s = fmaf(a.z, b4.z, s);
    s = fmaf(a.w, b4.w, s);
    if ((e >> 3) == h) {
      ushort4 u;
      u.x = f2bf(a.x); u.y = f2bf(a.y); u.z = f2bf(a.z); u.w = f2bf(a.w);
      *(ushort4*)(featb + (size_t)row * EE + e * 4) = u;
    }
  }
  tau2[idx] = (s + tau_b[h]) * 1.4426950408889634f;
  if (h == 0) {
    float2 c;
    c.x = bbox[(size_t)row * 4 + 0];
    c.y = bbox[(size_t)row * 4 + 1];
    cxy[row] = c;
  }
}

// ---------------------------------------------------------------------------
// Pairwise -dist, bf16, tiled to match attn fragments exactly:
// nds[((b*128+qt)*32 + jt)*1024 + lane*16 + (t*4+r)] = -dist(q15, jt*64+t*16+g*4+r)
// Computed ONCE per (b,i,j); shared by all 8 heads in attn.
// ---------------------------------------------------------------------------
__global__ __launch_bounds__(256) void dist_kernel(const float2* __restrict__ cxy,
                                                   unsigned short* __restrict__ nds) {
  int bq = blockIdx.x;
  int b = bq >> 7, qt = bq & 127;
  int tid = threadIdx.x;
  int w = tid >> 6, lane = tid & 63;
  int q15 = lane & 15, g = lane >> 4;
  int jt = blockIdx.y * 4 + w;

  float2 ci = cxy[b * NN + qt * 16 + q15];
  const float2* cb = cxy + b * NN + jt * 64;

  float nd[16];
#pragma unroll
  for (int t = 0; t < 4; ++t) {
    float4 c01 = *(const float4*)(cb + t * 16 + g * 4);
    float4 c23 = *(const float4*)(cb + t * 16 + g * 4 + 2);
    float cx[4] = {c01.x, c01.z, c23.x, c23.z};
    float cy[4] = {c01.y, c01.w, c23.y, c23.w};
#pragma unroll
    for (int r = 0; r < 4; ++r) {
      float dx = ci.x - cx[r], dy = ci.y - cy[r];
      nd[t * 4 + r] = -__builtin_amdgcn_sqrtf(fmaf(dy, dy, dx * dx));
    }
  }
  unsigned int u[8];
#pragma unroll
  for (int i = 0; i < 8; ++i)
    asm("v_cvt_pk_bf16_f32 %0, %1, %2" : "=v"(u[i]) : "v"(nd[2 * i]), "v"(nd[2 * i + 1]));
  unsigned short* dst = nds + ((size_t)(b * 128 + qt) * 32 + jt) * 1024 + lane * 16;
  *(uint4*)dst = make_uint4(u[0], u[1], u[2], u[3]);
  *(uint4*)(dst + 8) = make_uint4(u[4], u[5], u[6], u[7]);
}

// ---------------------------------------------------------------------------
// bf16 MFMA GEMM (validated round 7). MODE 0: qkv epilogue -> qb/kh/vpi, with
// Q pre-scaled by (1/sqrt(D))*log2e. MODE 1: out = v + resid (fp32).
// ---------------------------------------------------------------------------
template <int MODE>
__global__ __launch_bounds__(256) void gemm_mfma_kernel(const unsigned short* __restrict__ Ab,
                                                        const unsigned short* __restrict__ Wb,
                                                        const float* __restrict__ bias,
                                                        const float* __restrict__ resid,
                                                        float* __restrict__ Cf,
                                                        unsigned short* __restrict__ qb,
                                                        unsigned short* __restrict__ kh,
                                                        unsigned short* __restrict__ vpi) {
  int tid = threadIdx.x;
  int wv = tid >> 6, lane = tid & 63;
  int p = lane & 15, g = lane >> 4;
  int mW = blockIdx.y * 64 + wv * 16;
  int nB = blockIdx.x * 64;

  const unsigned short* ap = Ab + (size_t)(mW + p) * 256 + g * 8;
  const unsigned short* wp = Wb + (size_t)(nB + p) * 256 + g * 8;

  f32x4 acc[4] = {{0.f, 0.f, 0.f, 0.f}, {0.f, 0.f, 0.f, 0.f},
                  {0.f, 0.f, 0.f, 0.f}, {0.f, 0.f, 0.f, 0.f}};
#pragma unroll
  for (int kk = 0; kk < 8; ++kk) {
    short8 af = *(const short8*)(ap + kk * 32);
#pragma unroll
    for (int t = 0; t < 4; ++t) {
      short8 wf = *(const short8*)(wp + (size_t)t * 16 * 256 + kk * 32);
      acc[t] = __builtin_amdgcn_mfma_f32_16x16x32_bf16(af, wf, acc[t], 0, 0, 0);
    }
  }

#pragma unroll
  for (int t = 0; t < 4; ++t) {
    int n = nB + t * 16 + p;
    float bn = bias[n];
#pragma unroll
    for (int r = 0; r < 4; ++r) {
      int m = mW + g * 4 + r;
      float v = acc[t][r] + bn;
      if (MODE == 1) {
        Cf[(size_t)m * 256 + n] = v + resid[(size_t)m * 256 + n];
      } else {
        int b = m >> 11, tok = m & 2047;
        if (n < 256) {
          // Q: fold in 1/sqrt(32) * log2e so attn score = st + nd*tau2 directly
          qb[(size_t)m * 256 + n] = f2bf(v * 0.25506659272582955f);
        } else if (n < 512) {
          int h = (n - 256) >> 5, d = n & 31;
          kh[((size_t)(b * 8 + h) * NN + tok) * 32 + d] = f2bf(v);
        } else {
          int h = (n - 512) >> 5, d = n & 31;
          int cp = ((tok & 15) << 1) | ((tok >> 4) & 1);
          vpi[(((size_t)(b * 8 + h) * 64 + (tok >> 5)) * 32 + d) * 32 + cp] = f2bf(v);
        }
      }
    }
  }
}

// ---------------------------------------------------------------------------
// MFMA flash attention, fixed-reference softmax (clamped, NaN-proof).
// GRID SWAPPED vs round 8: x = qt (fast), y = bh (slow). Flat block id =
// qt + 128*bh, so the 8 heads sharing one (b,qt) nds tile are 128 apart
// = same XCD (id % 8 equal) -> nds is fetched from HBM once per XCD, not 8x.
// ---------------------------------------------------------------------------
__global__ __launch_bounds__(256) void attn_kernel(const unsigned short* __restrict__ qb,
                                                   const unsigned short* __restrict__ kh,
                                                   const unsigned short* __restrict__ vpi,
                                                   const unsigned short* __restrict__ nds,
                                                   const float* __restrict__ tau2,
                                                   unsigned short* __restrict__ ob) {
  __shared__ float accT[4][32][17];
  __shared__ float lT[4][16];
  __shared__ float linv[16];

  int bh = blockIdx.y;
  int b = bh >> 3, h = bh & 7;
  int qtb = blockIdx.x;
  int tid = threadIdx.x;
  int w = tid >> 6;
  int lane = tid & 63;
  int q15 = lane & 15, g = lane >> 4;
  int rowq = b * NN + qtb * 16 + q15;

  short8 qf = *(const short8*)(qb + (size_t)rowq * 256 + h * 32 + g * 8);
  float t2 = tau2[(size_t)rowq * HH + h];

  float l = 0.f;
  f32x4 acc0 = {0.f, 0.f, 0.f, 0.f}, acc1 = {0.f, 0.f, 0.f, 0.f};

  const unsigned short* kb = kh + (size_t)bh * NN * 32 + q15 * 32 + g * 8;
  const unsigned short* vb = vpi + (size_t)bh * NN * 32 + q15 * 32 + g * 8;
  const unsigned short* ndb = nds + (size_t)(b * 128 + qtb) * 32 * 1024 + lane * 16;

  int j0base = w * 512;

  short8 kf[2][4];
  short8 vf[2][2];

#pragma unroll
  for (int t = 0; t < 4; ++t)
    kf[0][t] = *(const short8*)(kb + (size_t)(j0base + t * 16) * 32);

#pragma unroll
  for (int tt = 0; tt < 8; ++tt) {
    const int cur = tt & 1, nxt = cur ^ 1;
    const int j0 = j0base + tt * 64;
    const int jt = j0 >> 6;
    if (tt < 7) {
#pragma unroll
      for (int t = 0; t < 4; ++t)
        kf[nxt][t] = *(const short8*)(kb + (size_t)(j0 + 64 + t * 16) * 32);
    }
#pragma unroll
    for (int t2i = 0; t2i < 2; ++t2i)
#pragma unroll
      for (int dh = 0; dh < 2; ++dh)
        vf[t2i][dh] = *(const short8*)(vb + (size_t)((j0 >> 5) + t2i) * 1024 + dh * 512);
    // -dist frags (bf16, lane-contiguous 32B)
    short8 n0 = *(const short8*)(ndb + (size_t)jt * 1024);
    short8 n1 = *(const short8*)(ndb + (size_t)jt * 1024 + 8);
    // ---- S^T tiles: 4x mfma (A = K rows, B = Q-prescaled) ----
    f32x4 st[4];
#pragma unroll
    for (int t = 0; t < 4; ++t)
      st[t] = __builtin_amdgcn_mfma_f32_16x16x32_bf16(kf[cur][t], qf, (f32x4){0.f, 0.f, 0.f, 0.f}, 0, 0, 0);
    // ---- score + exp2 (fixed reference, clamped) ----
    float p[16], lsum = 0.f;
#pragma unroll
    for (int i = 0; i < 16; ++i) {
      float ndf = bf2f(i < 8 ? n0[i] : n1[i - 8]);
      float e = fminf(fmaf(ndf, t2, st[i >> 2][i & 3]), 30.f);
      p[i] = __builtin_amdgcn_exp2f(e);
      lsum += p[i];
    }
    l += lsum;
    // ---- pack P to bf16 B-frags: u[wq] pairs keys (k, k+16) ----
    union { short8 v; unsigned int u[4]; } pf[2];
#pragma unroll
    for (int t2i = 0; t2i < 2; ++t2i)
#pragma unroll
      for (int wq = 0; wq < 4; ++wq) {
        float lo = p[t2i * 8 + wq];
        float hi = p[t2i * 8 + 4 + wq];
        asm("v_cvt_pk_bf16_f32 %0, %1, %2" : "=v"(pf[t2i].u[wq]) : "v"(lo), "v"(hi));
      }
    // ---- PV: 4x mfma, acc in O^T layout (col=q, row=d) ----
    acc0 = __builtin_amdgcn_mfma_f32_16x16x32_bf16(vf[0][0], pf[0].v, acc0, 0, 0, 0);
    acc1 = __builtin_amdgcn_mfma_f32_16x16x32_bf16(vf[0][1], pf[0].v, acc1, 0, 0, 0);
    acc0 = __builtin_amdgcn_mfma_f32_16x16x32_bf16(vf[1][0], pf[1].v, acc0, 0, 0, 0);
    acc1 = __builtin_amdgcn_mfma_f32_16x16x32_bf16(vf[1][1], pf[1].v, acc1, 0, 0, 0);
  }

  l += __shfl_xor(l, 16);
  l += __shfl_xor(l, 32);

#pragma unroll
  for (int r = 0; r < 4; ++r) {
    accT[w][g * 4 + r][q15] = acc0[r];
    accT[w][16 + g * 4 + r][q15] = acc1[r];
  }
  if (g == 0) lT[w][q15] = l;
  __syncthreads();

  if (tid < 16) {
    float L = lT[0][tid] + lT[1][tid] + lT[2][tid] + lT[3][tid];
    linv[tid] = 1.f / fmaxf(L, 1e-30f);
  }
  __syncthreads();

#pragma unroll
  for (int ii = 0; ii < 2; ++ii) {
    int i = tid + ii * 256;
    int q = i >> 5, d = i & 31;
    float ov = (accT[0][d][q] + accT[1][d][q] + accT[2][d][q] + accT[3][d][q]) * linv[q];
    ob[((size_t)b * NN + qtb * 16 + q) * EE + h * 32 + d] = f2bf(ov);
  }
}

extern "C" void kernel_launch(void* const* d_in, const int* in_sizes, int n_in,
                              void* d_out, int out_size, void* d_ws, size_t ws_size,
                              hipStream_t stream) {
  const float* bbox  = (const float*)d_in[0];
  const float* feat  = (const float*)d_in[1];
  const float* in_w  = (const float*)d_in[2];
  const float* in_b  = (const float*)d_in[3];
  const float* out_w = (const float*)d_in[4];
  const float* out_b = (const float*)d_in[5];
  const float* tau_w = (const float*)d_in[6];
  const float* tau_b = (const float*)d_in[7];
  float* out = (float*)d_out;

  unsigned short* ob     = (unsigned short*)d_ws;   // 1M bf16
  unsigned short* featb  = ob + 1048576;            // 1M bf16
  unsigned short* qb     = featb + 1048576;         // 1M bf16
  unsigned short* kh     = qb + 1048576;            // 1M bf16
  unsigned short* vpi    = kh + 1048576;            // 1M bf16
  unsigned short* in_wb  = vpi + 1048576;           // 196608 bf16
  unsigned short* out_wb = in_wb + 196608;          // 65536 bf16
  float* tau2 = (float*)(out_wb + 65536);           // 32768 f32
  float2* cxy = (float2*)(tau2 + 32768);            // 4096 float2
  unsigned short* nds = (unsigned short*)(cxy + 4096);  // 8,388,608 bf16 (16.8MB)

  cast_w_kernel<<<dim3(256), 256, 0, stream>>>(in_w, out_w, in_wb, out_wb);
  tau_cxy_kernel<<<dim3(128), 256, 0, stream>>>(feat, tau_w, tau_b, bbox, tau2, cxy, featb);
  dist_kernel<<<dim3(BB * 128, 8), 256, 0, stream>>>(cxy, nds);
  gemm_mfma_kernel<0><<<dim3(12, 64), 256, 0, stream>>>(featb, in_wb, in_b, nullptr, nullptr,
                                                        qb, kh, vpi);
  attn_kernel<<<dim3(NN / 16, BB * HH), 256, 0, stream>>>(qb, kh, vpi, nds, tau2, ob);
  gemm_mfma_kernel<1><<<dim3(4, 64), 256, 0, stream>>>(ob, out_wb, out_b, feat, out,
                                                       nullptr, nullptr, nullptr);
}

// Round 10
// 82.247 us; speedup vs baseline: 1.1987x; 1.1263x over previous
//
#include <hip/hip_runtime.h>
#include <math.h>

#define BB 2
#define NN 2048
#define EE 256
#define HH 8
#define DD 32

typedef __attribute__((ext_vector_type(8))) short short8;
typedef __attribute__((ext_vector_type(4))) float f32x4;

__device__ inline unsigned short f2bf(float f) {
  union { float f; unsigned int u; } a; a.f = f;
  unsigned int r = a.u + 0x7FFFu + ((a.u >> 16) & 1u);
  return (unsigned short)(r >> 16);
}
__device__ inline float bf2f(short s) {
  union { unsigned int u; float f; } a;
  a.u = ((unsigned int)(unsigned short)s) << 16;
  return a.f;
}

// ---------------------------------------------------------------------------
// Fused prep kernel, block-range dispatch (all segments independent):
//  blocks [0,256):    cast in_w/out_w -> bf16
//  blocks [256,384):  tau2 = (feat.tau_w[h] + tau_b[h])*log2e; featb = bf16(feat)
//  blocks [384,2432): nds pairwise -dist tiles (reads bbox directly)
// ---------------------------------------------------------------------------
__global__ __launch_bounds__(256) void prep_kernel(const float* __restrict__ bbox,
                                                   const float* __restrict__ feat,
                                                   const float* __restrict__ in_w,
                                                   const float* __restrict__ out_w,
                                                   const float* __restrict__ tau_w,
                                                   const float* __restrict__ tau_b,
                                                   unsigned short* __restrict__ in_wb,
                                                   unsigned short* __restrict__ out_wb,
                                                   float* __restrict__ tau2,
                                                   unsigned short* __restrict__ featb,
                                                   unsigned short* __restrict__ nds) {
  int blk = blockIdx.x;
  int tid = threadIdx.x;
  if (blk < 256) {
    // ---- weight cast ----
    int i = blk * 256 + tid;
    float4 v;
    unsigned short* dst;
    if (i < 49152) {
      v = ((const float4*)in_w)[i];
      dst = in_wb + (size_t)i * 4;
    } else {
      v = ((const float4*)out_w)[i - 49152];
      dst = out_wb + (size_t)(i - 49152) * 4;
    }
    ushort4 u;
    u.x = f2bf(v.x); u.y = f2bf(v.y); u.z = f2bf(v.z); u.w = f2bf(v.w);
    *(ushort4*)dst = u;
  } else if (blk < 384) {
    // ---- tau + feat cast ----
    int idx = (blk - 256) * 256 + tid;
    int row = idx >> 3, h = idx & 7;
    const float4* f = (const float4*)(feat + (size_t)row * EE);
    const float4* w = (const float4*)(tau_w + (size_t)h * EE);
    float s = 0.f;
#pragma unroll 8
    for (int e = 0; e < EE / 4; ++e) {
      float4 a = f[e], b4 = w[e];
      s = fmaf(a.x, b4.x, s);
      s = fmaf(a.y, b4.y, s);
      s = fmaf(a.z, b4.z, s);
      s = fmaf(a.w, b4.w, s);
      if ((e >> 3) == h) {
        ushort4 u;
        u.x = f2bf(a.x); u.y = f2bf(a.y); u.z = f2bf(a.z); u.w = f2bf(a.w);
        *(ushort4*)(featb + (size_t)row * EE + e * 4) = u;
      }
    }
    tau2[idx] = (s + tau_b[h]) * 1.4426950408889634f;
  } else {
    // ---- nds: -dist tiles, frag-layout bf16 ----
    int blk2 = blk - 384;
    int bq = blk2 >> 3;                 // (b*128 + qt)
    int yy = blk2 & 7;
    int b = bq >> 7, qt = bq & 127;
    int w = tid >> 6, lane = tid & 63;
    int q15 = lane & 15, g = lane >> 4;
    int jt = yy * 4 + w;

    const float* bi = bbox + (size_t)(b * NN + qt * 16 + q15) * 4;
    float cix = bi[0], ciy = bi[1];
    const float* bj = bbox + (size_t)(b * NN + jt * 64) * 4;

    float nd[16];
#pragma unroll
    for (int t = 0; t < 4; ++t) {
#pragma unroll
      for (int r = 0; r < 4; ++r) {
        int j = t * 16 + g * 4 + r;
        float2 cj = *(const float2*)(bj + (size_t)j * 4);
        float dx = cix - cj.x, dy = ciy - cj.y;
        nd[t * 4 + r] = -__builtin_amdgcn_sqrtf(fmaf(dy, dy, dx * dx));
      }
    }
    unsigned int u[8];
#pragma unroll
    for (int i = 0; i < 8; ++i)
      asm("v_cvt_pk_bf16_f32 %0, %1, %2" : "=v"(u[i]) : "v"(nd[2 * i]), "v"(nd[2 * i + 1]));
    unsigned short* dst = nds + ((size_t)(b * 128 + qt) * 32 + jt) * 1024 + lane * 16;
    *(uint4*)dst = make_uint4(u[0], u[1], u[2], u[3]);
    *(uint4*)(dst + 8) = make_uint4(u[4], u[5], u[6], u[7]);
  }
}

// ---------------------------------------------------------------------------
// bf16 MFMA GEMM (validated round 7). MODE 0: qkv epilogue -> qb/kh/vpi, with
// Q pre-scaled by (1/sqrt(D))*log2e. MODE 1: out = v + resid (fp32).
// ---------------------------------------------------------------------------
template <int MODE>
__global__ __launch_bounds__(256) void gemm_mfma_kernel(const unsigned short* __restrict__ Ab,
                                                        const unsigned short* __restrict__ Wb,
                                                        const float* __restrict__ bias,
                                                        const float* __restrict__ resid,
                                                        float* __restrict__ Cf,
                                                        unsigned short* __restrict__ qb,
                                                        unsigned short* __restrict__ kh,
                                                        unsigned short* __restrict__ vpi) {
  int tid = threadIdx.x;
  int wv = tid >> 6, lane = tid & 63;
  int p = lane & 15, g = lane >> 4;
  int mW = blockIdx.y * 64 + wv * 16;
  int nB = blockIdx.x * 64;

  const unsigned short* ap = Ab + (size_t)(mW + p) * 256 + g * 8;
  const unsigned short* wp = Wb + (size_t)(nB + p) * 256 + g * 8;

  f32x4 acc[4] = {{0.f, 0.f, 0.f, 0.f}, {0.f, 0.f, 0.f, 0.f},
                  {0.f, 0.f, 0.f, 0.f}, {0.f, 0.f, 0.f, 0.f}};
#pragma unroll
  for (int kk = 0; kk < 8; ++kk) {
    short8 af = *(const short8*)(ap + kk * 32);
#pragma unroll
    for (int t = 0; t < 4; ++t) {
      short8 wf = *(const short8*)(wp + (size_t)t * 16 * 256 + kk * 32);
      acc[t] = __builtin_amdgcn_mfma_f32_16x16x32_bf16(af, wf, acc[t], 0, 0, 0);
    }
  }

#pragma unroll
  for (int t = 0; t < 4; ++t) {
    int n = nB + t * 16 + p;
    float bn = bias[n];
#pragma unroll
    for (int r = 0; r < 4; ++r) {
      int m = mW + g * 4 + r;
      float v = acc[t][r] + bn;
      if (MODE == 1) {
        Cf[(size_t)m * 256 + n] = v + resid[(size_t)m * 256 + n];
      } else {
        int b = m >> 11, tok = m & 2047;
        if (n < 256) {
          qb[(size_t)m * 256 + n] = f2bf(v * 0.25506659272582955f);
        } else if (n < 512) {
          int h = (n - 256) >> 5, d = n & 31;
          kh[((size_t)(b * 8 + h) * NN + tok) * 32 + d] = f2bf(v);
        } else {
          int h = (n - 512) >> 5, d = n & 31;
          int cp = ((tok & 15) << 1) | ((tok >> 4) & 1);
          vpi[(((size_t)(b * 8 + h) * 64 + (tok >> 5)) * 32 + d) * 32 + cp] = f2bf(v);
        }
      }
    }
  }
}

// ---------------------------------------------------------------------------
// MFMA flash attention, QBLK=32: each block handles 32 queries (2 subtiles of
// 16) x one head; 4 waves K-split (wave w: keys [w*512,+512)). K/V stream is
// shared by both subtiles -> 2x arithmetic intensity vs round 9. Fixed-ref
// clamped softmax (validated r8/r9). Grid (qt32=x, bh=y): heads sharing an
// nds tile stay on one XCD.
// ---------------------------------------------------------------------------
__global__ __launch_bounds__(256) void attn_kernel(const unsigned short* __restrict__ qb,
                                                   const unsigned short* __restrict__ kh,
                                                   const unsigned short* __restrict__ vpi,
                                                   const unsigned short* __restrict__ nds,
                                                   const float* __restrict__ tau2,
                                                   unsigned short* __restrict__ ob) {
  __shared__ float accT[4][32][33];  // [wave][d][s*16+q15]
  __shared__ float lT[4][32];
  __shared__ float linv[32];

  int bh = blockIdx.y;
  int b = bh >> 3, h = bh & 7;
  int qtb = blockIdx.x;              // 32-query tile
  int tid = threadIdx.x;
  int w = tid >> 6;
  int lane = tid & 63;
  int q15 = lane & 15, g = lane >> 4;

  int row0 = b * NN + qtb * 32 + q15;        // subtile 0 row
  int row1 = row0 + 16;                      // subtile 1 row

  short8 qf0 = *(const short8*)(qb + (size_t)row0 * 256 + h * 32 + g * 8);
  short8 qf1 = *(const short8*)(qb + (size_t)row1 * 256 + h * 32 + g * 8);
  float t20 = tau2[(size_t)row0 * HH + h];
  float t21 = tau2[(size_t)row1 * HH + h];

  float l0 = 0.f, l1 = 0.f;
  f32x4 acc00 = {0.f, 0.f, 0.f, 0.f}, acc01 = {0.f, 0.f, 0.f, 0.f};
  f32x4 acc10 = {0.f, 0.f, 0.f, 0.f}, acc11 = {0.f, 0.f, 0.f, 0.f};

  const unsigned short* kb = kh + (size_t)bh * NN * 32 + q15 * 32 + g * 8;
  const unsigned short* vb = vpi + (size_t)bh * NN * 32 + q15 * 32 + g * 8;
  const unsigned short* ndb0 = nds + (size_t)(b * 128 + qtb * 2) * 32768 + lane * 16;
  const unsigned short* ndb1 = ndb0 + 32768;

  int j0base = w * 512;

  short8 kf[2][4];
  short8 vf[2][2];

#pragma unroll
  for (int t = 0; t < 4; ++t)
    kf[0][t] = *(const short8*)(kb + (size_t)(j0base + t * 16) * 32);

#pragma unroll
  for (int tt = 0; tt < 8; ++tt) {
    const int cur = tt & 1, nxt = cur ^ 1;
    const int j0 = j0base + tt * 64;
    const int jt = j0 >> 6;
    if (tt < 7) {
#pragma unroll
      for (int t = 0; t < 4; ++t)
        kf[nxt][t] = *(const short8*)(kb + (size_t)(j0 + 64 + t * 16) * 32);
    }
#pragma unroll
    for (int t2i = 0; t2i < 2; ++t2i)
#pragma unroll
      for (int dh = 0; dh < 2; ++dh)
        vf[t2i][dh] = *(const short8*)(vb + (size_t)((j0 >> 5) + t2i) * 1024 + dh * 512);
    // -dist frags for both subtiles
    short8 na0 = *(const short8*)(ndb0 + (size_t)jt * 1024);
    short8 na1 = *(const short8*)(ndb0 + (size_t)jt * 1024 + 8);
    short8 nb0 = *(const short8*)(ndb1 + (size_t)jt * 1024);
    short8 nb1 = *(const short8*)(ndb1 + (size_t)jt * 1024 + 8);

    // ---- S^T: 8x mfma (4 per subtile) ----
    f32x4 st0[4], st1[4];
#pragma unroll
    for (int t = 0; t < 4; ++t) {
      st0[t] = __builtin_amdgcn_mfma_f32_16x16x32_bf16(kf[cur][t], qf0, (f32x4){0.f, 0.f, 0.f, 0.f}, 0, 0, 0);
      st1[t] = __builtin_amdgcn_mfma_f32_16x16x32_bf16(kf[cur][t], qf1, (f32x4){0.f, 0.f, 0.f, 0.f}, 0, 0, 0);
    }
    // ---- score + exp2, subtile 0 ----
    float p0[16], p1[16];
    float ls0 = 0.f, ls1 = 0.f;
#pragma unroll
    for (int i = 0; i < 16; ++i) {
      float nda = bf2f(i < 8 ? na0[i] : na1[i - 8]);
      float e0 = fminf(fmaf(nda, t20, st0[i >> 2][i & 3]), 30.f);
      p0[i] = __builtin_amdgcn_exp2f(e0);
      ls0 += p0[i];
      float ndbv = bf2f(i < 8 ? nb0[i] : nb1[i - 8]);
      float e1 = fminf(fmaf(ndbv, t21, st1[i >> 2][i & 3]), 30.f);
      p1[i] = __builtin_amdgcn_exp2f(e1);
      ls1 += p1[i];
    }
    l0 += ls0;
    l1 += ls1;
    // ---- pack P -> bf16 frags (pairs keys k,k+16) ----
    union { short8 v; unsigned int u[4]; } pf0[2], pf1[2];
#pragma unroll
    for (int t2i = 0; t2i < 2; ++t2i)
#pragma unroll
      for (int wq = 0; wq < 4; ++wq) {
        asm("v_cvt_pk_bf16_f32 %0, %1, %2"
            : "=v"(pf0[t2i].u[wq]) : "v"(p0[t2i * 8 + wq]), "v"(p0[t2i * 8 + 4 + wq]));
        asm("v_cvt_pk_bf16_f32 %0, %1, %2"
            : "=v"(pf1[t2i].u[wq]) : "v"(p1[t2i * 8 + wq]), "v"(p1[t2i * 8 + 4 + wq]));
      }
    // ---- PV: 8x mfma ----
    acc00 = __builtin_amdgcn_mfma_f32_16x16x32_bf16(vf[0][0], pf0[0].v, acc00, 0, 0, 0);
    acc01 = __builtin_amdgcn_mfma_f32_16x16x32_bf16(vf[0][1], pf0[0].v, acc01, 0, 0, 0);
    acc10 = __builtin_amdgcn_mfma_f32_16x16x32_bf16(vf[0][0], pf1[0].v, acc10, 0, 0, 0);
    acc11 = __builtin_amdgcn_mfma_f32_16x16x32_bf16(vf[0][1], pf1[0].v, acc11, 0, 0, 0);
    acc00 = __builtin_amdgcn_mfma_f32_16x16x32_bf16(vf[1][0], pf0[1].v, acc00, 0, 0, 0);
    acc01 = __builtin_amdgcn_mfma_f32_16x16x32_bf16(vf[1][1], pf0[1].v, acc01, 0, 0, 0);
    acc10 = __builtin_amdgcn_mfma_f32_16x16x32_bf16(vf[1][0], pf1[1].v, acc10, 0, 0, 0);
    acc11 = __builtin_amdgcn_mfma_f32_16x16x32_bf16(vf[1][1], pf1[1].v, acc11, 0, 0, 0);
  }

  // reduce l across g-groups (acc holds full key-sum per d,q)
  l0 += __shfl_xor(l0, 16);
  l0 += __shfl_xor(l0, 32);
  l1 += __shfl_xor(l1, 16);
  l1 += __shfl_xor(l1, 32);

#pragma unroll
  for (int r = 0; r < 4; ++r) {
    accT[w][g * 4 + r][q15] = acc00[r];
    accT[w][16 + g * 4 + r][q15] = acc01[r];
    accT[w][g * 4 + r][16 + q15] = acc10[r];
    accT[w][16 + g * 4 + r][16 + q15] = acc11[r];
  }
  if (g == 0) {
    lT[w][q15] = l0;
    lT[w][16 + q15] = l1;
  }
  __syncthreads();

  if (tid < 32) {
    float L = lT[0][tid] + lT[1][tid] + lT[2][tid] + lT[3][tid];
    linv[tid] = 1.f / fmaxf(L, 1e-30f);
  }
  __syncthreads();

#pragma unroll
  for (int ii = 0; ii < 4; ++ii) {
    int i = tid + ii * 256;
    int q = i >> 5, d = i & 31;
    float ov = (accT[0][d][q] + accT[1][d][q] + accT[2][d][q] + accT[3][d][q]) * linv[q];
    ob[((size_t)b * NN + qtb * 32 + q) * EE + h * 32 + d] = f2bf(ov);
  }
}

extern "C" void kernel_launch(void* const* d_in, const int* in_sizes, int n_in,
                              void* d_out, int out_size, void* d_ws, size_t ws_size,
                              hipStream_t stream) {
  const float* bbox  = (const float*)d_in[0];
  const float* feat  = (const float*)d_in[1];
  const float* in_w  = (const float*)d_in[2];
  const float* in_b  = (const float*)d_in[3];
  const float* out_w = (const float*)d_in[4];
  const float* out_b = (const float*)d_in[5];
  const float* tau_w = (const float*)d_in[6];
  const float* tau_b = (const float*)d_in[7];
  float* out = (float*)d_out;

  unsigned short* ob     = (unsigned short*)d_ws;   // 1M bf16
  unsigned short* featb  = ob + 1048576;            // 1M bf16
  unsigned short* qb     = featb + 1048576;         // 1M bf16
  unsigned short* kh     = qb + 1048576;            // 1M bf16
  unsigned short* vpi    = kh + 1048576;            // 1M bf16
  unsigned short* in_wb  = vpi + 1048576;           // 196608 bf16
  unsigned short* out_wb = in_wb + 196608;          // 65536 bf16
  float* tau2 = (float*)(out_wb + 65536);           // 32768 f32
  unsigned short* nds = (unsigned short*)(tau2 + 32768);  // 8,388,608 bf16

  prep_kernel<<<dim3(2432), 256, 0, stream>>>(bbox, feat, in_w, out_w, tau_w, tau_b,
                                              in_wb, out_wb, tau2, featb, nds);
  gemm_mfma_kernel<0><<<dim3(12, 64), 256, 0, stream>>>(featb, in_wb, in_b, nullptr, nullptr,
                                                        qb, kh, vpi);
  attn_kernel<<<dim3(NN / 32, BB * HH), 256, 0, stream>>>(qb, kh, vpi, nds, tau2, ob);
  gemm_mfma_kernel<1><<<dim3(4, 64), 256, 0, stream>>>(ob, out_wb, out_b, feat, out,
                                                       nullptr, nullptr, nullptr);
}